// Round 5
// baseline (99.850 us; speedup 1.0000x reference)
//
#include <hip/hip_runtime.h>
#include <hip/hip_bf16.h>

#define IM 1024
#define NSEG 128
#define EPSF 1e-10f

// ws layout (floats):
//   [0]            bf16 flag (uint)
//   [64 .. 1088)   per-row min  (1024)
//   [2048 .. 3072) per-row max  (1024)
//   [4096 .. +1M)  fp32 template (path A)
#define WS_FLAG 0
#define WS_BMIN 64
#define WS_BMAX 2048
#define WS_TMPL 4096

__device__ __forceinline__ float bf16_decode(unsigned short u) {
    return __uint_as_float(((unsigned)u) << 16);
}

// Per-segment constants in LDS (3 x float4 per segment):
//   cT = (dx, dy, c0n, L2e)       c0n = -(dx*x0+dy*y0), L2e = dx^2+dy^2+EPS
//   cI = (nx, dxL, crossL, inv_d) nx=-dy/L, dxL=dx/L, crossL=(dy*x0-dx*y0)/L
//   cE = (x0, y0, x1, y1)
__device__ __forceinline__ int setup_consts(const void* xs_raw, const void* ys_raw,
                                            float4* cT, float4* cI, float4* cE,
                                            float* sx, float* sy, int* sflag) {
    int tx = threadIdx.x;
    if (tx == 0) *sflag = 1;
    __syncthreads();
    if (tx <= NSEG) {
        unsigned short ux = ((const unsigned short*)xs_raw)[tx];
        unsigned short uy = ((const unsigned short*)ys_raw)[tx];
        float fx = bf16_decode(ux), fy = bf16_decode(uy);
        bool plaus = (fx >= 0.0f) && (fx <= 1024.0f) && (fy >= 0.0f) && (fy <= 1024.0f);
        if (!plaus) atomicAnd(sflag, 0);
        sx[tx] = fx; sy[tx] = fy;
    }
    __syncthreads();
    int flag = *sflag;
    if (!flag && tx <= NSEG) {
        sx[tx] = ((const float*)xs_raw)[tx];
        sy[tx] = ((const float*)ys_raw)[tx];
    }
    __syncthreads();
    if (tx < NSEG) {
        float x0 = sx[tx], y0 = sy[tx], x1 = sx[tx + 1], y1 = sy[tx + 1];
        float dx = x1 - x0, dy = y1 - y0;
        float L2e = dx * dx + dy * dy + EPSF;
        float inv_d = 1.0f / L2e;
        float invL = 1.0f / __builtin_amdgcn_sqrtf(L2e);
        cT[tx] = make_float4(dx, dy, -(dx * x0 + dy * y0), L2e);
        cI[tx] = make_float4(-dy * invL, dx * invL, (dy * x0 - dx * y0) * invL, inv_d);
        cE[tx] = make_float4(x0, y0, x1, y1);
    }
    __syncthreads();
    return flag;
}

// Render 4 CONTIGUOUS pixels per thread: x = 4*tx .. 4*tx+3, row yp.
// Wave-uniform region classification: q = dx*x + rb monotone in x, so testing
// q at the wave's 256-px window ends decides interior / endpoint / mixed for
// the whole wave. Interior: d = |perpendicular| (linear, NO sqrt).
__device__ __forceinline__ void render4(const float4* cT, const float4* cI,
                                        const float4* cE,
                                        float yp, float acc[4]) {
    int tx = threadIdx.x;
    float xb = (float)(4 * tx);
    float xp1 = xb + 1.f, xp2 = xb + 2.f, xp3 = xb + 3.f;
    float wlo = (float)((tx >> 6) << 8);   // wave window [wlo, wlo+255]
    float whi = wlo + 255.0f;
    float a0 = 0.f, a1 = 0.f, a2 = 0.f, a3 = 0.f;

    for (int s = 0; s < NSEG; ++s) {
        float4 T = cT[s];
        float4 I = cI[s];
        float4 E = cE[s];
        float rb = fmaf(T.y, yp, T.z);
        float q0 = fmaf(T.x, wlo, rb);
        float q1 = fmaf(T.x, whi, rb);
        float qmn = fminf(q0, q1), qmx = fmaxf(q0, q1);
        int cls = (qmn >= 0.f && qmx <= T.w) ? 0 : (qmx <= 0.f) ? 1
                : (qmn >= T.w) ? 2 : 3;
        cls = __builtin_amdgcn_readfirstlane(cls);
        if (cls == 0) {
            // interior: d = |nx*x + (dxL*yp + crossL)|
            float wr = fmaf(I.y, yp, I.z);
            a0 += fabsf(fmaf(I.x, xb, wr));
            a1 += fabsf(fmaf(I.x, xp1, wr));
            a2 += fabsf(fmaf(I.x, xp2, wr));
            a3 += fabsf(fmaf(I.x, xp3, wr));
        } else if (cls != 3) {
            // whole wave nearest one endpoint
            float xe = (cls == 1) ? E.x : E.z;
            float ye = (cls == 1) ? E.y : E.w;
            float ey = yp - ye;
            float ey2 = fmaf(ey, ey, EPSF);
            float e0 = xb - xe, e1 = xp1 - xe, e2 = xp2 - xe, e3 = xp3 - xe;
            a0 += __builtin_amdgcn_sqrtf(fmaf(e0, e0, ey2));
            a1 += __builtin_amdgcn_sqrtf(fmaf(e1, e1, ey2));
            a2 += __builtin_amdgcn_sqrtf(fmaf(e2, e2, ey2));
            a3 += __builtin_amdgcn_sqrtf(fmaf(e3, e3, ey2));
        } else {
            // mixed: full clamped form
            float inv_d = I.w;
            {
                float t  = __builtin_amdgcn_fmed3f(fmaf(T.x, xb, rb) * inv_d, 0.f, 1.f);
                float dx = xb - fmaf(t, T.x, E.x), dy = yp - fmaf(t, T.y, E.y);
                a0 += __builtin_amdgcn_sqrtf(fmaf(dx, dx, fmaf(dy, dy, EPSF)));
            }
            {
                float t  = __builtin_amdgcn_fmed3f(fmaf(T.x, xp1, rb) * inv_d, 0.f, 1.f);
                float dx = xp1 - fmaf(t, T.x, E.x), dy = yp - fmaf(t, T.y, E.y);
                a1 += __builtin_amdgcn_sqrtf(fmaf(dx, dx, fmaf(dy, dy, EPSF)));
            }
            {
                float t  = __builtin_amdgcn_fmed3f(fmaf(T.x, xp2, rb) * inv_d, 0.f, 1.f);
                float dx = xp2 - fmaf(t, T.x, E.x), dy = yp - fmaf(t, T.y, E.y);
                a2 += __builtin_amdgcn_sqrtf(fmaf(dx, dx, fmaf(dy, dy, EPSF)));
            }
            {
                float t  = __builtin_amdgcn_fmed3f(fmaf(T.x, xp3, rb) * inv_d, 0.f, 1.f);
                float dx = xp3 - fmaf(t, T.x, E.x), dy = yp - fmaf(t, T.y, E.y);
                a3 += __builtin_amdgcn_sqrtf(fmaf(dx, dx, fmaf(dy, dy, EPSF)));
            }
        }
    }
    acc[0] = a0; acc[1] = a1; acc[2] = a2; acc[3] = a3;
}

template <bool STORE>
__global__ __launch_bounds__(256, 4) void k_render(const void* __restrict__ xs_raw,
                                                   const void* __restrict__ ys_raw,
                                                   float* __restrict__ ws) {
    __shared__ float4 cT[NSEG], cI[NSEG], cE[NSEG];
    __shared__ float sx[NSEG + 1], sy[NSEG + 1];
    __shared__ int sflag;
    __shared__ float swmn[4], swmx[4];

    int tx = threadIdx.x;
    int y = blockIdx.x;
    int flag = setup_consts(xs_raw, ys_raw, cT, cI, cE, sx, sy, &sflag);

    float acc[4];
    render4(cT, cI, cE, (float)y, acc);

    float tmn = fminf(fminf(acc[0], acc[1]), fminf(acc[2], acc[3]));
    float tmx = fmaxf(fmaxf(acc[0], acc[1]), fmaxf(acc[2], acc[3]));
    for (int off = 32; off > 0; off >>= 1) {
        tmn = fminf(tmn, __shfl_down(tmn, off));
        tmx = fmaxf(tmx, __shfl_down(tmx, off));
    }
    if ((tx & 63) == 0) { swmn[tx >> 6] = tmn; swmx[tx >> 6] = tmx; }
    __syncthreads();
    if (tx == 0) {
        float m = fminf(fminf(swmn[0], swmn[1]), fminf(swmn[2], swmn[3]));
        float M = fmaxf(fmaxf(swmx[0], swmx[1]), fmaxf(swmx[2], swmx[3]));
        ws[WS_BMIN + y] = m;
        ws[WS_BMAX + y] = M;
        if (y == 0) ((unsigned*)ws)[WS_FLAG] = (unsigned)flag;
    }
    if (STORE) {
        *(float4*)(ws + WS_TMPL + y * IM + 4 * tx) =
            make_float4(acc[0], acc[1], acc[2], acc[3]);
    }
}

__device__ __forceinline__ void global_minmax(const float* __restrict__ ws,
                                              float* swmn, float* swmx, float* sred,
                                              float& tmin, float& scale) {
    int tx = threadIdx.x;
    float mn = 1e30f, mx = -1e30f;
#pragma unroll
    for (int i = 0; i < 4; ++i) {
        mn = fminf(mn, ws[WS_BMIN + tx + 256 * i]);
        mx = fmaxf(mx, ws[WS_BMAX + tx + 256 * i]);
    }
    for (int off = 32; off > 0; off >>= 1) {
        mn = fminf(mn, __shfl_down(mn, off));
        mx = fmaxf(mx, __shfl_down(mx, off));
    }
    if ((tx & 63) == 0) { swmn[tx >> 6] = mn; swmx[tx >> 6] = mx; }
    __syncthreads();
    if (tx == 0) {
        float m = fminf(fminf(swmn[0], swmn[1]), fminf(swmn[2], swmn[3]));
        float M = fmaxf(fmaxf(swmx[0], swmx[1]), fmaxf(swmx[2], swmx[3]));
        sred[0] = m;
        sred[1] = 1.0f / (M - m);
    }
    __syncthreads();
    tmin = sred[0];
    scale = sred[1];
}

__global__ __launch_bounds__(256) void k_norm(const float* __restrict__ ws,
                                              void* __restrict__ out) {
    __shared__ float swmn[4], swmx[4], sred[2];
    float tmin, scale;
    global_minmax(ws, swmn, swmx, sred, tmin, scale);
    int flag = (int)((const unsigned*)ws)[WS_FLAG];
    int idx = (blockIdx.x * 256 + threadIdx.x) * 4;
    float4 t = *(const float4*)(ws + WS_TMPL + idx);
    float r0 = (t.x - tmin) * scale;
    float r1 = (t.y - tmin) * scale;
    float r2 = (t.z - tmin) * scale;
    float r3 = (t.w - tmin) * scale;
    if (flag) {
        __hip_bfloat16 h0 = __float2bfloat16(r0);
        __hip_bfloat16 h1 = __float2bfloat16(r1);
        __hip_bfloat16 h2 = __float2bfloat16(r2);
        __hip_bfloat16 h3 = __float2bfloat16(r3);
        ushort4 p;
        p.x = *(unsigned short*)&h0; p.y = *(unsigned short*)&h1;
        p.z = *(unsigned short*)&h2; p.w = *(unsigned short*)&h3;
        *(ushort4*)((unsigned short*)out + idx) = p;
    } else {
        *(float4*)((float*)out + idx) = make_float4(r0, r1, r2, r3);
    }
}

// Fallback when ws can't hold the template: recompute the row, then normalize.
__global__ __launch_bounds__(256, 4) void k_norm_recompute(const void* __restrict__ xs_raw,
                                                           const void* __restrict__ ys_raw,
                                                           const float* __restrict__ ws,
                                                           void* __restrict__ out) {
    __shared__ float4 cT[NSEG], cI[NSEG], cE[NSEG];
    __shared__ float sx[NSEG + 1], sy[NSEG + 1];
    __shared__ int sflag;
    __shared__ float swmn[4], swmx[4], sred[2];

    int tx = threadIdx.x;
    int y = blockIdx.x;
    int flag = setup_consts(xs_raw, ys_raw, cT, cI, cE, sx, sy, &sflag);
    float tmin, scale;
    global_minmax(ws, swmn, swmx, sred, tmin, scale);
    float acc[4];
    render4(cT, cI, cE, (float)y, acc);
    int base = y * IM + 4 * tx;
#pragma unroll
    for (int k = 0; k < 4; ++k) {
        float r = (acc[k] - tmin) * scale;
        if (flag) {
            __hip_bfloat16 h = __float2bfloat16(r);
            ((unsigned short*)out)[base + k] = *(unsigned short*)&h;
        } else {
            ((float*)out)[base + k] = r;
        }
    }
}

extern "C" void kernel_launch(void* const* d_in, const int* in_sizes, int n_in,
                              void* d_out, int out_size, void* d_ws, size_t ws_size,
                              hipStream_t stream) {
    const void* xs = d_in[0];
    const void* ys = d_in[1];
    float* wsf = (float*)d_ws;
    bool pathA = ws_size >= (size_t)(WS_TMPL + IM * IM) * sizeof(float);

    if (pathA) {
        hipLaunchKernelGGL((k_render<true>), dim3(IM), dim3(256), 0, stream, xs, ys, wsf);
        hipLaunchKernelGGL(k_norm, dim3(IM), dim3(256), 0, stream, wsf, d_out);
    } else {
        hipLaunchKernelGGL((k_render<false>), dim3(IM), dim3(256), 0, stream, xs, ys, wsf);
        hipLaunchKernelGGL(k_norm_recompute, dim3(IM), dim3(256), 0, stream,
                           xs, ys, wsf, d_out);
    }
}

// Round 6
// 67.397 us; speedup vs baseline: 1.4815x; 1.4815x over previous
//
#include <hip/hip_runtime.h>
#include <hip/hip_bf16.h>

#define IM 1024
#define NSEG 128
#define EPSF 1e-10f
#define H 4
#define CG 257   // coarse grid: samples at x,y = 0,4,...,1024

// ws layout (floats):
//   [0]               bf16 flag (uint)
//   [64 .. 64+CG)     per-coarse-row min   (fallback: per-fine-row, 1024)
//   [2048 .. 2048+CG) per-coarse-row max   (fallback: 1024)
//   [4096 .. +CG*CG)  coarse template (258 KB)
#define WS_FLAG 0
#define WS_BMIN 64
#define WS_BMAX 2048
#define WS_COARSE 4096

__device__ __forceinline__ float bf16_decode(unsigned short u) {
    return __uint_as_float(((unsigned)u) << 16);
}

// Per-segment constants in LDS:  cA = (dx, dy, x0, y0),  cB = (inv_d, c0n)
__device__ __forceinline__ int setup_consts(const void* xs_raw, const void* ys_raw,
                                            float4* cA, float2* cB,
                                            float* sx, float* sy, int* sflag) {
    int tx = threadIdx.x;
    if (tx == 0) *sflag = 1;
    __syncthreads();
    if (tx <= NSEG) {
        unsigned short ux = ((const unsigned short*)xs_raw)[tx];
        unsigned short uy = ((const unsigned short*)ys_raw)[tx];
        float fx = bf16_decode(ux), fy = bf16_decode(uy);
        bool plaus = (fx >= 0.0f) && (fx <= 1024.0f) && (fy >= 0.0f) && (fy <= 1024.0f);
        if (!plaus) atomicAnd(sflag, 0);
        sx[tx] = fx; sy[tx] = fy;
    }
    __syncthreads();
    int flag = *sflag;
    if (!flag && tx <= NSEG) {
        sx[tx] = ((const float*)xs_raw)[tx];
        sy[tx] = ((const float*)ys_raw)[tx];
    }
    __syncthreads();
    if (tx < NSEG) {
        float x0 = sx[tx], y0 = sy[tx], x1 = sx[tx + 1], y1 = sy[tx + 1];
        float dx = x1 - x0, dy = y1 - y0;
        float inv_d = 1.0f / (dx * dx + dy * dy + EPSF);
        float c0n = -(dx * x0 + dy * y0);
        cA[tx] = make_float4(dx, dy, x0, y0);
        cB[tx] = make_float2(inv_d, c0n);
    }
    __syncthreads();
    return flag;
}

// Coarse render: one sample per thread at (tx*4, row*4). Branchless R3 math.
__global__ __launch_bounds__(320, 4) void k_coarse(const void* __restrict__ xs_raw,
                                                   const void* __restrict__ ys_raw,
                                                   float* __restrict__ ws) {
    __shared__ float4 cA[NSEG];
    __shared__ float2 cB[NSEG];
    __shared__ float sx[NSEG + 1], sy[NSEG + 1];
    __shared__ int sflag;
    __shared__ float swmn[5], swmx[5];

    int tx = threadIdx.x;
    int row = blockIdx.x;
    int flag = setup_consts(xs_raw, ys_raw, cA, cB, sx, sy, &sflag);

    float yp = (float)(row * H);
    float xp = (float)(tx * H);
    float val = 0.0f;
#pragma unroll 8
    for (int s = 0; s < NSEG; ++s) {
        float4 A = cA[s];
        float2 B = cB[s];
        float rb = fmaf(A.y, yp, B.y);
        float t  = __builtin_amdgcn_fmed3f(fmaf(A.x, xp, rb) * B.x, 0.0f, 1.0f);
        float xc = fmaf(t, A.x, A.z), yc = fmaf(t, A.y, A.w);
        float ddx = xp - xc, ddy = yp - yc;
        val += __builtin_amdgcn_sqrtf(fmaf(ddx, ddx, fmaf(ddy, ddy, EPSF)));
    }

    bool valid = (tx < CG);
    float vmn = valid ? val : 1e30f;
    float vmx = valid ? val : -1e30f;
    for (int off = 32; off > 0; off >>= 1) {
        vmn = fminf(vmn, __shfl_down(vmn, off));
        vmx = fmaxf(vmx, __shfl_down(vmx, off));
    }
    if ((tx & 63) == 0) { swmn[tx >> 6] = vmn; swmx[tx >> 6] = vmx; }
    __syncthreads();
    if (tx == 0) {
        float m = swmn[0], M = swmx[0];
#pragma unroll
        for (int i = 1; i < 5; ++i) { m = fminf(m, swmn[i]); M = fmaxf(M, swmx[i]); }
        ws[WS_BMIN + row] = m;
        ws[WS_BMAX + row] = M;
        if (row == 0) ((unsigned*)ws)[WS_FLAG] = (unsigned)flag;
    }
    if (valid) ws[WS_COARSE + row * CG + tx] = val;
}

// Upsample: bilinear from coarse grid + normalize + store. 4 px/thread.
__global__ __launch_bounds__(256) void k_up(const float* __restrict__ ws,
                                            void* __restrict__ out) {
    __shared__ float swmn[4], swmx[4], sred[2];
    int tx = threadIdx.x;
    float mn = 1e30f, mx = -1e30f;
    for (int i = tx; i < CG; i += 256) {
        mn = fminf(mn, ws[WS_BMIN + i]);
        mx = fmaxf(mx, ws[WS_BMAX + i]);
    }
    for (int off = 32; off > 0; off >>= 1) {
        mn = fminf(mn, __shfl_down(mn, off));
        mx = fmaxf(mx, __shfl_down(mx, off));
    }
    if ((tx & 63) == 0) { swmn[tx >> 6] = mn; swmx[tx >> 6] = mx; }
    __syncthreads();
    if (tx == 0) {
        float m = fminf(fminf(swmn[0], swmn[1]), fminf(swmn[2], swmn[3]));
        float M = fmaxf(fmaxf(swmx[0], swmx[1]), fmaxf(swmx[2], swmx[3]));
        sred[0] = m;
        sred[1] = 1.0f / (M - m);
    }
    __syncthreads();
    float tmin = sred[0], scale = sred[1];
    int flag = (int)((const unsigned*)ws)[WS_FLAG];

    int y = blockIdx.x;
    int y4 = y >> 2;
    float wy = (float)(y & 3) * 0.25f;
    const float* g = ws + WS_COARSE + y4 * CG + tx;
    float c00 = g[0], c01 = g[1], c10 = g[CG], c11 = g[CG + 1];
    float a  = fmaf(wy, c10 - c00, c00);
    float b0 = c01 - c00, b1 = c11 - c10;
    float b  = fmaf(wy, b1 - b0, b0);
    float as = (a - tmin) * scale;
    float bs = b * scale;
    float r0 = as;
    float r1 = fmaf(bs, 0.25f, as);
    float r2 = fmaf(bs, 0.50f, as);
    float r3 = fmaf(bs, 0.75f, as);
    int idx = y * IM + 4 * tx;
    if (flag) {
        __hip_bfloat16 h0 = __float2bfloat16(r0);
        __hip_bfloat16 h1 = __float2bfloat16(r1);
        __hip_bfloat16 h2 = __float2bfloat16(r2);
        __hip_bfloat16 h3 = __float2bfloat16(r3);
        ushort4 p;
        p.x = *(unsigned short*)&h0; p.y = *(unsigned short*)&h1;
        p.z = *(unsigned short*)&h2; p.w = *(unsigned short*)&h3;
        *(ushort4*)((unsigned short*)out + idx) = p;
    } else {
        *(float4*)((float*)out + idx) = make_float4(r0, r1, r2, r3);
    }
}

// ---------- fallback path (tiny ws): exact render, proven in R3 ----------
__device__ __forceinline__ void render4(const float4* cA, const float2* cB,
                                        float yp, float xp0, float acc[4]) {
    float a0 = 0.f, a1 = 0.f, a2 = 0.f, a3 = 0.f;
    float xp1 = xp0 + 256.f, xp2 = xp0 + 512.f, xp3 = xp0 + 768.f;
#pragma unroll 8
    for (int s = 0; s < NSEG; ++s) {
        float4 A = cA[s];
        float2 B = cB[s];
        float rb = fmaf(A.y, yp, B.y);
        {
            float t  = __builtin_amdgcn_fmed3f(fmaf(A.x, xp0, rb) * B.x, 0.0f, 1.0f);
            float xc = fmaf(t, A.x, A.z), yc = fmaf(t, A.y, A.w);
            float dx = xp0 - xc, dy = yp - yc;
            a0 += __builtin_amdgcn_sqrtf(fmaf(dx, dx, fmaf(dy, dy, EPSF)));
        }
        {
            float t  = __builtin_amdgcn_fmed3f(fmaf(A.x, xp1, rb) * B.x, 0.0f, 1.0f);
            float xc = fmaf(t, A.x, A.z), yc = fmaf(t, A.y, A.w);
            float dx = xp1 - xc, dy = yp - yc;
            a1 += __builtin_amdgcn_sqrtf(fmaf(dx, dx, fmaf(dy, dy, EPSF)));
        }
        {
            float t  = __builtin_amdgcn_fmed3f(fmaf(A.x, xp2, rb) * B.x, 0.0f, 1.0f);
            float xc = fmaf(t, A.x, A.z), yc = fmaf(t, A.y, A.w);
            float dx = xp2 - xc, dy = yp - yc;
            a2 += __builtin_amdgcn_sqrtf(fmaf(dx, dx, fmaf(dy, dy, EPSF)));
        }
        {
            float t  = __builtin_amdgcn_fmed3f(fmaf(A.x, xp3, rb) * B.x, 0.0f, 1.0f);
            float xc = fmaf(t, A.x, A.z), yc = fmaf(t, A.y, A.w);
            float dx = xp3 - xc, dy = yp - yc;
            a3 += __builtin_amdgcn_sqrtf(fmaf(dx, dx, fmaf(dy, dy, EPSF)));
        }
    }
    acc[0] = a0; acc[1] = a1; acc[2] = a2; acc[3] = a3;
}

__global__ __launch_bounds__(256, 4) void k_render_minmax(const void* __restrict__ xs_raw,
                                                          const void* __restrict__ ys_raw,
                                                          float* __restrict__ ws) {
    __shared__ float4 cA[NSEG];
    __shared__ float2 cB[NSEG];
    __shared__ float sx[NSEG + 1], sy[NSEG + 1];
    __shared__ int sflag;
    __shared__ float swmn[4], swmx[4];
    int tx = threadIdx.x;
    int y = blockIdx.x;
    int flag = setup_consts(xs_raw, ys_raw, cA, cB, sx, sy, &sflag);
    float acc[4];
    render4(cA, cB, (float)y, (float)tx, acc);
    float tmn = fminf(fminf(acc[0], acc[1]), fminf(acc[2], acc[3]));
    float tmx = fmaxf(fmaxf(acc[0], acc[1]), fmaxf(acc[2], acc[3]));
    for (int off = 32; off > 0; off >>= 1) {
        tmn = fminf(tmn, __shfl_down(tmn, off));
        tmx = fmaxf(tmx, __shfl_down(tmx, off));
    }
    if ((tx & 63) == 0) { swmn[tx >> 6] = tmn; swmx[tx >> 6] = tmx; }
    __syncthreads();
    if (tx == 0) {
        float m = fminf(fminf(swmn[0], swmn[1]), fminf(swmn[2], swmn[3]));
        float M = fmaxf(fmaxf(swmx[0], swmx[1]), fmaxf(swmx[2], swmx[3]));
        ws[WS_BMIN + y] = m;
        ws[WS_BMAX + y] = M;
        if (y == 0) ((unsigned*)ws)[WS_FLAG] = (unsigned)flag;
    }
}

__global__ __launch_bounds__(256, 4) void k_norm_recompute(const void* __restrict__ xs_raw,
                                                           const void* __restrict__ ys_raw,
                                                           const float* __restrict__ ws,
                                                           void* __restrict__ out) {
    __shared__ float4 cA[NSEG];
    __shared__ float2 cB[NSEG];
    __shared__ float sx[NSEG + 1], sy[NSEG + 1];
    __shared__ int sflag;
    __shared__ float swmn[4], swmx[4], sred[2];
    int tx = threadIdx.x;
    int y = blockIdx.x;
    int flag = setup_consts(xs_raw, ys_raw, cA, cB, sx, sy, &sflag);
    float mn = 1e30f, mx = -1e30f;
#pragma unroll
    for (int i = 0; i < 4; ++i) {
        mn = fminf(mn, ws[WS_BMIN + tx + 256 * i]);
        mx = fmaxf(mx, ws[WS_BMAX + tx + 256 * i]);
    }
    for (int off = 32; off > 0; off >>= 1) {
        mn = fminf(mn, __shfl_down(mn, off));
        mx = fmaxf(mx, __shfl_down(mx, off));
    }
    if ((tx & 63) == 0) { swmn[tx >> 6] = mn; swmx[tx >> 6] = mx; }
    __syncthreads();
    if (tx == 0) {
        float m = fminf(fminf(swmn[0], swmn[1]), fminf(swmn[2], swmn[3]));
        float M = fmaxf(fmaxf(swmx[0], swmx[1]), fmaxf(swmx[2], swmx[3]));
        sred[0] = m; sred[1] = 1.0f / (M - m);
    }
    __syncthreads();
    float tmin = sred[0], scale = sred[1];
    float acc[4];
    render4(cA, cB, (float)y, (float)tx, acc);
#pragma unroll
    for (int k = 0; k < 4; ++k) {
        float r = (acc[k] - tmin) * scale;
        int idx = y * IM + tx + 256 * k;
        if (flag) {
            __hip_bfloat16 h = __float2bfloat16(r);
            ((unsigned short*)out)[idx] = *(unsigned short*)&h;
        } else {
            ((float*)out)[idx] = r;
        }
    }
}

extern "C" void kernel_launch(void* const* d_in, const int* in_sizes, int n_in,
                              void* d_out, int out_size, void* d_ws, size_t ws_size,
                              hipStream_t stream) {
    const void* xs = d_in[0];
    const void* ys = d_in[1];
    float* wsf = (float*)d_ws;
    bool coarse_ok = ws_size >= (size_t)(WS_COARSE + CG * CG + 64) * sizeof(float);

    if (coarse_ok) {
        hipLaunchKernelGGL(k_coarse, dim3(CG), dim3(320), 0, stream, xs, ys, wsf);
        hipLaunchKernelGGL(k_up, dim3(IM), dim3(256), 0, stream, wsf, d_out);
    } else {
        hipLaunchKernelGGL(k_render_minmax, dim3(IM), dim3(256), 0, stream, xs, ys, wsf);
        hipLaunchKernelGGL(k_norm_recompute, dim3(IM), dim3(256), 0, stream,
                           xs, ys, wsf, d_out);
    }
}